// Round 3
// baseline (288.286 us; speedup 1.0000x reference)
//
#include <hip/hip_runtime.h>
#include <hip/hip_bf16.h>

#define D_MODEL 1024
#define NHEADS  16
#define HD      64
#define BATCH   2
#define SEQ     2048
#define NTOK    (BATCH * SEQ)   // 4096

typedef __attribute__((ext_vector_type(8))) short bf16x8;
typedef __attribute__((ext_vector_type(4))) float f32x4;

#if __has_builtin(__builtin_amdgcn_exp2f)
#define EXP2F(x) __builtin_amdgcn_exp2f(x)   // raw v_exp_f32
#else
#define EXP2F(x) exp2f(x)
#endif

static __device__ __forceinline__ short f2bf(float f) {
    union { float f; unsigned u; } x; x.f = f;
    unsigned r = (x.u + 0x7fffu + ((x.u >> 16) & 1u)) >> 16;  // RNE
    return (short)r;
}

// pack two fp32 -> bf16 pair (RNE), as one dword
static __device__ __forceinline__ unsigned pk_bf16(float a, float b) {
    __hip_bfloat162 h2 = __float22bfloat162_rn(make_float2(a, b));
    union { __hip_bfloat162 h; unsigned u; } c; c.h = h2;
    return c.u;
}

// async global->LDS, 16B per lane; LDS dest = wave-uniform base + lane*16
static __device__ __forceinline__ void gl_lds16(const short* g, short* l) {
    __builtin_amdgcn_global_load_lds((const __attribute__((address_space(1))) void*)g,
                                     (__attribute__((address_space(3))) void*)l,
                                     16, 0, 0);
}

// ---------------------------------------------------------------------------
// Fused prep: cast x -> bf16 (blocks 0..4095), transpose+cast Wqkv with
// softmax scale folded into Q-columns (blocks 4096..7167), transpose+cast Wo
// (blocks 7168..8191). One launch instead of three.
// ---------------------------------------------------------------------------
__global__ __launch_bounds__(256) void prep_kernel(const float* __restrict__ x,
                                                   short* __restrict__ x_bf,
                                                   const float* __restrict__ Wqkv,
                                                   short* __restrict__ WqkvT,
                                                   const float* __restrict__ Wo,
                                                   short* __restrict__ WoT,
                                                   float cexp) {
    int bid = blockIdx.x;
    int tid = threadIdx.x;

    if (bid < 4096) {
        int i = bid * 256 + tid;
        float4 v = ((const float4*)x)[i];
        short4 o;
        o.x = f2bf(v.x); o.y = f2bf(v.y); o.z = f2bf(v.z); o.w = f2bf(v.w);
        ((short4*)x_bf)[i] = o;
        return;
    }

    __shared__ float tile[32][33];
    const float* in; short* out; int R, C, slimit; float sc; int bx, by;
    if (bid < 4096 + 3072) {
        int idx = bid - 4096;
        in = Wqkv; out = WqkvT; R = D_MODEL; C = 3 * D_MODEL;
        slimit = D_MODEL; sc = cexp;
        bx = idx % 96; by = idx / 96;
    } else {
        int idx = bid - 7168;
        in = Wo; out = WoT; R = D_MODEL; C = D_MODEL;
        slimit = 0; sc = 1.0f;
        bx = idx % 32; by = idx / 32;
    }
    int bc = bx * 32, br = by * 32;
    int tx = tid & 31, ty = tid >> 5;   // 32 x 8
    #pragma unroll
    for (int i = 0; i < 32; i += 8)
        tile[ty + i][tx] = in[(long)(br + ty + i) * C + bc + tx];
    __syncthreads();
    #pragma unroll
    for (int i = 0; i < 32; i += 8) {
        int orow = bc + ty + i;
        float v = tile[tx][ty + i];
        if (orow < slimit) v *= sc;
        out[(long)orow * R + br + tx] = f2bf(v);
    }
}

// ---------------------------------------------------------------------------
// Output-proj GEMM: 128x64 tiles (512 blocks = 2/CU). Wave w: rows
// [w*32, w*32+32), all 64 cols -> 2x4 frags.
// ---------------------------------------------------------------------------
__global__ __launch_bounds__(256) void gemm_out(const short* __restrict__ A,
                                                const short* __restrict__ BT,
                                                float* __restrict__ C,
                                                int M, int N, int K) {
    __shared__ short As[128 * 32];
    __shared__ short Bs[64 * 32];

    int tid  = threadIdx.x;
    int lane = tid & 63;
    int w    = tid >> 6;
    int quad = lane >> 4;
    int l16  = lane & 15;

    int m_blk = blockIdx.y * 128, n_blk = blockIdx.x * 64;

    const short* Ag = A  + (long)(m_blk + w * 32 + (lane >> 2)) * K + (lane & 3) * 8;
    const short* Bg = BT + (long)(n_blk + w * 16 + (lane >> 2)) * K + (lane & 3) * 8;
    short* AsW = &As[(w * 32) * 32];
    short* BsW = &Bs[(w * 16) * 32];

    f32x4 acc[2][4] = {};

    for (int k0 = 0; k0 < K; k0 += 32) {
        __syncthreads();
        gl_lds16(Ag + k0,          AsW);
        gl_lds16(Ag + 16 * K + k0, AsW + 16 * 32);
        gl_lds16(Bg + k0,          BsW);
        __syncthreads();

        bf16x8 a[2], b[4];
        #pragma unroll
        for (int i = 0; i < 2; i++)
            a[i] = *(const bf16x8*)&As[(w * 32 + i * 16 + l16) * 32 + quad * 8];
        #pragma unroll
        for (int j = 0; j < 4; j++)
            b[j] = *(const bf16x8*)&Bs[(j * 16 + l16) * 32 + quad * 8];
        #pragma unroll
        for (int i = 0; i < 2; i++)
            #pragma unroll
            for (int j = 0; j < 4; j++)
                acc[i][j] = __builtin_amdgcn_mfma_f32_16x16x32_bf16(a[i], b[j], acc[i][j], 0, 0, 0);
    }

    #pragma unroll
    for (int i = 0; i < 2; i++)
        #pragma unroll
        for (int j = 0; j < 4; j++)
            #pragma unroll
            for (int r = 0; r < 4; r++) {
                int row = m_blk + w * 32 + i * 16 + quad * 4 + r;
                int col = n_blk + j * 16 + l16;
                C[(long)row * N + col] = acc[i][j][r];
            }
}

// ---------------------------------------------------------------------------
// QKV GEMM: m97 structure, bf16 out split into Qb/Kb/Vb by n-range.
// ---------------------------------------------------------------------------
__global__ __launch_bounds__(256) void gemm_qkv(const short* __restrict__ A,
                                                const short* __restrict__ BT,
                                                short* __restrict__ Qb,
                                                short* __restrict__ Kb,
                                                short* __restrict__ Vb) {
    const int K = 1024;
    __shared__ short As[128 * 32];
    __shared__ short Bs[128 * 32];

    int tid  = threadIdx.x;
    int lane = tid & 63;
    int w    = tid >> 6;
    int quad = lane >> 4;
    int l16  = lane & 15;

    int m_blk = blockIdx.y * 128, n_blk = blockIdx.x * 128;
    int mh = (w >> 1) * 64, nh = (w & 1) * 64;

    int sel = blockIdx.x >> 3;                 // 0:Q 1:K 2:V
    short* outb = (sel == 0) ? Qb : (sel == 1) ? Kb : Vb;
    int ncol0 = n_blk - sel * 1024;

    const short* Ag = A  + (long)(m_blk + w * 32 + (lane >> 2)) * K + (lane & 3) * 8;
    const short* Bg = BT + (long)(n_blk + w * 32 + (lane >> 2)) * K + (lane & 3) * 8;
    short* AsW = &As[(w * 32) * 32];
    short* BsW = &Bs[(w * 32) * 32];

    f32x4 acc[4][4] = {};

    for (int k0 = 0; k0 < K; k0 += 32) {
        __syncthreads();
        gl_lds16(Ag + k0,          AsW);
        gl_lds16(Ag + 16 * K + k0, AsW + 16 * 32);
        gl_lds16(Bg + k0,          BsW);
        gl_lds16(Bg + 16 * K + k0, BsW + 16 * 32);
        __syncthreads();

        bf16x8 a[4], b[4];
        #pragma unroll
        for (int i = 0; i < 4; i++)
            a[i] = *(const bf16x8*)&As[(mh + i * 16 + l16) * 32 + quad * 8];
        #pragma unroll
        for (int j = 0; j < 4; j++)
            b[j] = *(const bf16x8*)&Bs[(nh + j * 16 + l16) * 32 + quad * 8];
        #pragma unroll
        for (int i = 0; i < 4; i++)
            #pragma unroll
            for (int j = 0; j < 4; j++)
                acc[i][j] = __builtin_amdgcn_mfma_f32_16x16x32_bf16(a[i], b[j], acc[i][j], 0, 0, 0);
    }

    #pragma unroll
    for (int i = 0; i < 4; i++)
        #pragma unroll
        for (int j = 0; j < 4; j++)
            #pragma unroll
            for (int r = 0; r < 4; r++) {
                int row = m_blk + mh + i * 16 + quad * 4 + r;
                int col = ncol0 + nh + j * 16 + l16;
                outb[(long)row * 1024 + col] = f2bf(acc[i][j][r]);
            }
}

// ---------------------------------------------------------------------------
// Repack K and V into MFMA-B-fragment-ready tiles (per bh, per 64-key tile):
//   Kt2 chunks u: element = K[(u>>2)*32+((u>>1)&1)*16+l16][(u&1)*32+quad*8+j]
//   Vt2 chunks (c,j): element = V[key(s)][j*16+l16], s=c*32+quad*8+jj,
//     key(s) = (s>>2)+((s&3)<<4)   (matches flash's b64 P-pack order)
// ---------------------------------------------------------------------------
__global__ __launch_bounds__(256) void repack_kv(const short* __restrict__ Kb,
                                                 const short* __restrict__ Vb,
                                                 short* __restrict__ Kt2,
                                                 short* __restrict__ Vt2) {
    __shared__ short Kl[64][72];
    __shared__ short Vl[64][72];
    int t = blockIdx.x, bh = blockIdx.y;
    int b = bh >> 4, h = bh & 15;
    int tid = threadIdx.x;

    int r  = tid >> 2;
    int cc = (tid & 3) * 16;
    const short* ks = Kb + ((long)b * SEQ + t * 64 + r) * 1024 + h * 64 + cc;
    const short* vs = Vb + ((long)b * SEQ + t * 64 + r) * 1024 + h * 64 + cc;
    *(bf16x8*)&Kl[r][cc]     = *(const bf16x8*)(ks);
    *(bf16x8*)&Kl[r][cc + 8] = *(const bf16x8*)(ks + 8);
    *(bf16x8*)&Vl[r][cc]     = *(const bf16x8*)(vs);
    *(bf16x8*)&Vl[r][cc + 8] = *(const bf16x8*)(vs + 8);
    __syncthreads();

    long obase = (long)bh * (SEQ * 64) + t * 4096;

    #pragma unroll
    for (int ch = 0; ch < 2; ch++) {
        int o = tid * 16 + ch * 8;
        int u = o >> 9, qd = (o >> 7) & 3, l = (o >> 3) & 15;
        int row = (u >> 2) * 32 + ((u >> 1) & 1) * 16 + l;
        int col = (u & 1) * 32 + qd * 8;
        *(bf16x8*)(Kt2 + obase + o) = *(const bf16x8*)&Kl[row][col];
    }
    #pragma unroll
    for (int ch = 0; ch < 2; ch++) {
        int o = tid * 16 + ch * 8;
        int c = o >> 11, j = (o >> 9) & 3, qd = (o >> 7) & 3, l = (o >> 3) & 15;
        int hd = j * 16 + l;
        bf16x8 ov;
        #pragma unroll
        for (int jj = 0; jj < 8; jj++) {
            int s = c * 32 + qd * 8 + jj;
            int key = (s >> 2) + ((s & 3) << 4);
            ov[jj] = Vl[key][hd];
        }
        *(bf16x8*)(Vt2 + obase + o) = ov;
    }
}

// ---------------------------------------------------------------------------
// Flash attention: fragment-direct, 32 q/block, 4-way K-split.
//   Occupancy is register-capped at 4 waves/SIMD (64 arch + ~64 acc regs);
//   rounds 0-2 showed raising it via launch_bounds spills. So this round
//   attacks latency instead:
//   (1) XCD-chunked block swizzle (T1): 1D grid 2048, nid=(bid&7)*256+bid>>3
//       -> all 64 q-tile blocks of one bh (512 KB K/V) land on ONE XCD's L2;
//       4 bh/XCD = 2 MB < 4 MB L2. Round-2 FETCH=70MB = 4.4x working set
//       proved every XCD was refetching every bh from HBM (~900cy loads).
//   (2) kf cross-iteration prefetch: issue next tile's K frags right after
//       vf, in-place into the same kf regs (footprint flat); their vmcnt
//       wait lands after ~1000cy of exp/pack/PV instead of immediately.
//   (3) s_setprio(1) around MFMA clusters (T5; barrier-free desynced waves,
//       the m191-positive regime).
// ---------------------------------------------------------------------------
__global__ __launch_bounds__(256, 4) void flash_attn(const short* __restrict__ Qb,
                                                     const short* __restrict__ Kt2,
                                                     const short* __restrict__ Vt2,
                                                     short* __restrict__ y) {
    int tid  = threadIdx.x;
    int lane = tid & 63;
    int w    = tid >> 6;        // ksel = w (4-way key split)
    int quad = lane >> 4;
    int l16  = lane & 15;

    // T1: bijective XCD-chunked swizzle (2048 % 8 == 0)
    int bid0 = blockIdx.x;
    int nid  = (bid0 & 7) * 256 + (bid0 >> 3);
    int bh = nid >> 6;          // 4 consecutive bh per XCD
    int b  = bh >> 4;
    int h  = bh & 15;
    int qw = (nid & 63) * 32;

    __shared__ union {
        short Ps[4][32 * 72];   // wave-private P tiles (18432 B)
        float Mg[2][64][20];    // merge half-buffers (10240 B), used after loop
    } sh;
    short* PsW = &sh.Ps[w][0];

    const short* Qrow = Qb + ((long)b * SEQ + qw + l16) * 1024 + h * 64;
    bf16x8 aQ[2][2];
    #pragma unroll
    for (int m = 0; m < 2; m++)
        #pragma unroll
        for (int c = 0; c < 2; c++)
            aQ[m][c] = *(const bf16x8*)(Qrow + (long)(m * 16) * 1024 + c * 32 + quad * 8);

    const short* Ktb = Kt2 + (long)bh * (SEQ * 64) + (long)w * 8 * 4096;
    const short* Vtb = Vt2 + (long)bh * (SEQ * 64) + (long)w * 8 * 4096;

    f32x4 O[2][4] = {};
    f32x4 Lacc[2] = {};
    bf16x8 ones;
    #pragma unroll
    for (int i = 0; i < 8; i++) ones[i] = (short)0x3F80;   // bf16 1.0

    // prologue: K frags for t=0
    bf16x8 kf[8];
    #pragma unroll
    for (int u = 0; u < 8; u++) kf[u] = *(const bf16x8*)(Ktb + u * 512 + lane * 8);

    for (int t = 0; t < 8; t++) {
        const short* Vt  = Vtb + t * 4096;
        const short* Ktn = Ktb + (t + 1) * 4096;

        // S = Q K^T: 2 m-frags x 4 key-cols, 2 chained d-chunks each
        __builtin_amdgcn_s_setprio(1);
        f32x4 z[2][4];
        #pragma unroll
        for (int m = 0; m < 2; m++)
            #pragma unroll
            for (int kc = 0; kc < 4; kc++) {
                f32x4 zz = {};
                zz = __builtin_amdgcn_mfma_f32_16x16x32_bf16(aQ[m][0], kf[2 * kc],     zz, 0, 0, 0);
                z[m][kc] = __builtin_amdgcn_mfma_f32_16x16x32_bf16(aQ[m][1], kf[2 * kc + 1], zz, 0, 0, 0);
            }
        __builtin_amdgcn_s_setprio(0);

        // V fragment loads — issued now, consumed after exp/pack (latency hidden)
        bf16x8 vf[8];
        #pragma unroll
        for (int u = 0; u < 8; u++) vf[u] = *(const bf16x8*)(Vt + u * 512 + lane * 8);

        // kf prefetch for t+1, in-place (kf dead after S-MFMAs above);
        // vmcnt wait for these lands at next iteration's S-MFMAs.
        if (t < 7) {
            #pragma unroll
            for (int u = 0; u < 8; u++) kf[u] = *(const bf16x8*)(Ktn + u * 512 + lane * 8);
        }

        // p = exp2(z) (raw v_exp_f32); packed bf16 cvt; one b64 write per (m,r)
        #pragma unroll
        for (int m = 0; m < 2; m++)
            #pragma unroll
            for (int r = 0; r < 4; r++) {
                unsigned d0 = pk_bf16(EXP2F(z[m][0][r]), EXP2F(z[m][1][r]));
                unsigned d1 = pk_bf16(EXP2F(z[m][2][r]), EXP2F(z[m][3][r]));
                unsigned long long dd = ((unsigned long long)d1 << 32) | d0;
                *(unsigned long long*)((unsigned*)PsW + (m * 16 + quad * 4 + r) * 36 + 2 * l16) = dd;
            }

        // PV + row-sum (ones-column MFMA); bV shared across both m-frags
        __builtin_amdgcn_s_setprio(1);
        #pragma unroll
        for (int c = 0; c < 2; c++) {
            bf16x8 aP0 = *(const bf16x8*)(PsW + (l16) * 72      + c * 32 + quad * 8);
            bf16x8 aP1 = *(const bf16x8*)(PsW + (16 + l16) * 72 + c * 32 + quad * 8);
            Lacc[0] = __builtin_amdgcn_mfma_f32_16x16x32_bf16(aP0, ones, Lacc[0], 0, 0, 0);
            Lacc[1] = __builtin_amdgcn_mfma_f32_16x16x32_bf16(aP1, ones, Lacc[1], 0, 0, 0);
            #pragma unroll
            for (int j = 0; j < 4; j++) {
                O[0][j] = __builtin_amdgcn_mfma_f32_16x16x32_bf16(aP0, vf[c * 4 + j], O[0][j], 0, 0, 0);
                O[1][j] = __builtin_amdgcn_mfma_f32_16x16x32_bf16(aP1, vf[c * 4 + j], O[1][j], 0, 0, 0);
            }
        }
        __builtin_amdgcn_s_setprio(0);
    }

    // ---- pairwise merge of 4 key-split partials (Ps dead, reuse as Mg) ----
    // Round 1: w1 -> Mg[0] (read by w0), w3 -> Mg[1] (read by w2), per m-half.
    __syncthreads();
    #pragma unroll
    for (int m = 0; m < 2; m++) {
        if (w == 1 || w == 3) {
            float* mg = &sh.Mg[w >> 1][lane][0];
            #pragma unroll
            for (int j = 0; j < 4; j++)
                #pragma unroll
                for (int r = 0; r < 4; r++)
                    mg[j * 4 + r] = O[m][j][r];
            #pragma unroll
            for (int r = 0; r < 4; r++)
                mg[16 + r] = Lacc[m][r];
        }
        __syncthreads();
        if (w == 0 || w == 2) {
            const float* mg = &sh.Mg[w >> 1][lane][0];
            #pragma unroll
            for (int j = 0; j < 4; j++)
                #pragma unroll
                for (int r = 0; r < 4; r++)
                    O[m][j][r] += mg[j * 4 + r];
            #pragma unroll
            for (int r = 0; r < 4; r++)
                Lacc[m][r] += mg[16 + r];
        }
        __syncthreads();
    }
    // Round 2: w2 holds (w2+w3); write both m-halves, w0 accumulates all.
    if (w == 2) {
        #pragma unroll
        for (int m = 0; m < 2; m++) {
            float* mg = &sh.Mg[m][lane][0];
            #pragma unroll
            for (int j = 0; j < 4; j++)
                #pragma unroll
                for (int r = 0; r < 4; r++)
                    mg[j * 4 + r] = O[m][j][r];
            #pragma unroll
            for (int r = 0; r < 4; r++)
                mg[16 + r] = Lacc[m][r];
        }
    }
    __syncthreads();
    if (w == 0) {
        #pragma unroll
        for (int m = 0; m < 2; m++) {
            const float* mg = &sh.Mg[m][lane][0];
            #pragma unroll
            for (int j = 0; j < 4; j++)
                #pragma unroll
                for (int r = 0; r < 4; r++)
                    O[m][j][r] += mg[j * 4 + r];
            #pragma unroll
            for (int r = 0; r < 4; r++)
                Lacc[m][r] += mg[16 + r];
        }

        #pragma unroll
        for (int m = 0; m < 2; m++) {
            f32x4 rl;
            #pragma unroll
            for (int r = 0; r < 4; r++) rl[r] = 1.0f / Lacc[m][r];
            #pragma unroll
            for (int j = 0; j < 4; j++)
                #pragma unroll
                for (int r = 0; r < 4; r++) {
                    int row = qw + m * 16 + quad * 4 + r;
                    y[((long)b * SEQ + row) * D_MODEL + h * HD + j * 16 + l16] =
                        f2bf(O[m][j][r] * rl[r]);
                }
        }
    }
}

// ---------------------------------------------------------------------------
// Workspace (48 MB): Qb@0, Kb@8M (yb aliases after repack), Vb@16M,
// Kt2@24M, Vt2@32M, WqkvT@40M, WoT@46M. x_bf scratched in d_out.
// ---------------------------------------------------------------------------
extern "C" void kernel_launch(void* const* d_in, const int* in_sizes, int n_in,
                              void* d_out, int out_size, void* d_ws, size_t ws_size,
                              hipStream_t stream) {
    const float* x    = (const float*)d_in[0];
    const float* Wqkv = (const float*)d_in[1];
    const float* Wo   = (const float*)d_in[2];

    char* ws = (char*)d_ws;
    short* Qb    = (short*)(ws);
    short* Kb    = (short*)(ws + 8388608);
    short* Vb    = (short*)(ws + 16777216);
    short* Kt2   = (short*)(ws + 25165824);
    short* Vt2   = (short*)(ws + 33554432);
    short* WqkvT = (short*)(ws + 41943040);
    short* WoT   = (short*)(ws + 48234496);
    short* x_bf  = (short*)d_out;            // scratch in d_out (16 MB fp32)
    short* yb    = Kb;                       // Kb dead after repack_kv

    const float cexp = 0.125f * 1.4426950408889634f;  // 1/sqrt(64) * log2(e)

    prep_kernel<<<8192, 256, 0, stream>>>(x, x_bf, Wqkv, WqkvT, Wo, WoT, cexp);

    gemm_qkv<<<dim3(3 * D_MODEL / 128, NTOK / 128), 256, 0, stream>>>(
        x_bf, WqkvT, Qb, Kb, Vb);

    repack_kv<<<dim3(SEQ / 64, BATCH * NHEADS), 256, 0, stream>>>(Kb, Vb, Kt2, Vt2);

    flash_attn<<<2048, 256, 0, stream>>>(Qb, Kt2, Vt2, yb);

    gemm_out<<<dim3(D_MODEL / 64, NTOK / 128), 256, 0, stream>>>(
        yb, WoT, (float*)d_out, NTOK, D_MODEL, D_MODEL);
}

// Round 4
// 194.055 us; speedup vs baseline: 1.4856x; 1.4856x over previous
//
#include <hip/hip_runtime.h>
#include <hip/hip_bf16.h>

#define D_MODEL 1024
#define NHEADS  16
#define HD      64
#define BATCH   2
#define SEQ     2048
#define NTOK    (BATCH * SEQ)   // 4096

typedef __attribute__((ext_vector_type(8))) short bf16x8;
typedef __attribute__((ext_vector_type(4))) float f32x4;

#if __has_builtin(__builtin_amdgcn_exp2f)
#define EXP2F(x) __builtin_amdgcn_exp2f(x)   // raw v_exp_f32
#else
#define EXP2F(x) exp2f(x)
#endif

static __device__ __forceinline__ short f2bf(float f) {
    union { float f; unsigned u; } x; x.f = f;
    unsigned r = (x.u + 0x7fffu + ((x.u >> 16) & 1u)) >> 16;  // RNE
    return (short)r;
}

// pack two fp32 -> bf16 pair (RNE), as one dword
static __device__ __forceinline__ unsigned pk_bf16(float a, float b) {
    __hip_bfloat162 h2 = __float22bfloat162_rn(make_float2(a, b));
    union { __hip_bfloat162 h; unsigned u; } c; c.h = h2;
    return c.u;
}

// async global->LDS, 16B per lane; LDS dest = wave-uniform base + lane*16
static __device__ __forceinline__ void gl_lds16(const short* g, short* l) {
    __builtin_amdgcn_global_load_lds((const __attribute__((address_space(1))) void*)g,
                                     (__attribute__((address_space(3))) void*)l,
                                     16, 0, 0);
}

// ---------------------------------------------------------------------------
// Fused prep: cast x -> bf16 (blocks 0..4095), transpose+cast Wqkv with
// softmax scale folded into Q-columns (blocks 4096..7167), transpose+cast Wo
// (blocks 7168..8191). One launch instead of three.
// ---------------------------------------------------------------------------
__global__ __launch_bounds__(256) void prep_kernel(const float* __restrict__ x,
                                                   short* __restrict__ x_bf,
                                                   const float* __restrict__ Wqkv,
                                                   short* __restrict__ WqkvT,
                                                   const float* __restrict__ Wo,
                                                   short* __restrict__ WoT,
                                                   float cexp) {
    int bid = blockIdx.x;
    int tid = threadIdx.x;

    if (bid < 4096) {
        int i = bid * 256 + tid;
        float4 v = ((const float4*)x)[i];
        short4 o;
        o.x = f2bf(v.x); o.y = f2bf(v.y); o.z = f2bf(v.z); o.w = f2bf(v.w);
        ((short4*)x_bf)[i] = o;
        return;
    }

    __shared__ float tile[32][33];
    const float* in; short* out; int R, C, slimit; float sc; int bx, by;
    if (bid < 4096 + 3072) {
        int idx = bid - 4096;
        in = Wqkv; out = WqkvT; R = D_MODEL; C = 3 * D_MODEL;
        slimit = D_MODEL; sc = cexp;
        bx = idx % 96; by = idx / 96;
    } else {
        int idx = bid - 7168;
        in = Wo; out = WoT; R = D_MODEL; C = D_MODEL;
        slimit = 0; sc = 1.0f;
        bx = idx % 32; by = idx / 32;
    }
    int bc = bx * 32, br = by * 32;
    int tx = tid & 31, ty = tid >> 5;   // 32 x 8
    #pragma unroll
    for (int i = 0; i < 32; i += 8)
        tile[ty + i][tx] = in[(long)(br + ty + i) * C + bc + tx];
    __syncthreads();
    #pragma unroll
    for (int i = 0; i < 32; i += 8) {
        int orow = bc + ty + i;
        float v = tile[tx][ty + i];
        if (orow < slimit) v *= sc;
        out[(long)orow * R + br + tx] = f2bf(v);
    }
}

// ---------------------------------------------------------------------------
// Output-proj GEMM: 128x64 tiles (512 blocks = 2/CU). Wave w: rows
// [w*32, w*32+32), all 64 cols -> 2x4 frags.
// ---------------------------------------------------------------------------
__global__ __launch_bounds__(256) void gemm_out(const short* __restrict__ A,
                                                const short* __restrict__ BT,
                                                float* __restrict__ C,
                                                int M, int N, int K) {
    __shared__ short As[128 * 32];
    __shared__ short Bs[64 * 32];

    int tid  = threadIdx.x;
    int lane = tid & 63;
    int w    = tid >> 6;
    int quad = lane >> 4;
    int l16  = lane & 15;

    int m_blk = blockIdx.y * 128, n_blk = blockIdx.x * 64;

    const short* Ag = A  + (long)(m_blk + w * 32 + (lane >> 2)) * K + (lane & 3) * 8;
    const short* Bg = BT + (long)(n_blk + w * 16 + (lane >> 2)) * K + (lane & 3) * 8;
    short* AsW = &As[(w * 32) * 32];
    short* BsW = &Bs[(w * 16) * 32];

    f32x4 acc[2][4] = {};

    for (int k0 = 0; k0 < K; k0 += 32) {
        __syncthreads();
        gl_lds16(Ag + k0,          AsW);
        gl_lds16(Ag + 16 * K + k0, AsW + 16 * 32);
        gl_lds16(Bg + k0,          BsW);
        __syncthreads();

        bf16x8 a[2], b[4];
        #pragma unroll
        for (int i = 0; i < 2; i++)
            a[i] = *(const bf16x8*)&As[(w * 32 + i * 16 + l16) * 32 + quad * 8];
        #pragma unroll
        for (int j = 0; j < 4; j++)
            b[j] = *(const bf16x8*)&Bs[(j * 16 + l16) * 32 + quad * 8];
        #pragma unroll
        for (int i = 0; i < 2; i++)
            #pragma unroll
            for (int j = 0; j < 4; j++)
                acc[i][j] = __builtin_amdgcn_mfma_f32_16x16x32_bf16(a[i], b[j], acc[i][j], 0, 0, 0);
    }

    #pragma unroll
    for (int i = 0; i < 2; i++)
        #pragma unroll
        for (int j = 0; j < 4; j++)
            #pragma unroll
            for (int r = 0; r < 4; r++) {
                int row = m_blk + w * 32 + i * 16 + quad * 4 + r;
                int col = n_blk + j * 16 + l16;
                C[(long)row * N + col] = acc[i][j][r];
            }
}

// ---------------------------------------------------------------------------
// QKV GEMM: m97 structure, bf16 out split into Qb/Kb/Vb by n-range.
// ---------------------------------------------------------------------------
__global__ __launch_bounds__(256) void gemm_qkv(const short* __restrict__ A,
                                                const short* __restrict__ BT,
                                                short* __restrict__ Qb,
                                                short* __restrict__ Kb,
                                                short* __restrict__ Vb) {
    const int K = 1024;
    __shared__ short As[128 * 32];
    __shared__ short Bs[128 * 32];

    int tid  = threadIdx.x;
    int lane = tid & 63;
    int w    = tid >> 6;
    int quad = lane >> 4;
    int l16  = lane & 15;

    int m_blk = blockIdx.y * 128, n_blk = blockIdx.x * 128;
    int mh = (w >> 1) * 64, nh = (w & 1) * 64;

    int sel = blockIdx.x >> 3;                 // 0:Q 1:K 2:V
    short* outb = (sel == 0) ? Qb : (sel == 1) ? Kb : Vb;
    int ncol0 = n_blk - sel * 1024;

    const short* Ag = A  + (long)(m_blk + w * 32 + (lane >> 2)) * K + (lane & 3) * 8;
    const short* Bg = BT + (long)(n_blk + w * 32 + (lane >> 2)) * K + (lane & 3) * 8;
    short* AsW = &As[(w * 32) * 32];
    short* BsW = &Bs[(w * 32) * 32];

    f32x4 acc[4][4] = {};

    for (int k0 = 0; k0 < K; k0 += 32) {
        __syncthreads();
        gl_lds16(Ag + k0,          AsW);
        gl_lds16(Ag + 16 * K + k0, AsW + 16 * 32);
        gl_lds16(Bg + k0,          BsW);
        gl_lds16(Bg + 16 * K + k0, BsW + 16 * 32);
        __syncthreads();

        bf16x8 a[4], b[4];
        #pragma unroll
        for (int i = 0; i < 4; i++)
            a[i] = *(const bf16x8*)&As[(mh + i * 16 + l16) * 32 + quad * 8];
        #pragma unroll
        for (int j = 0; j < 4; j++)
            b[j] = *(const bf16x8*)&Bs[(nh + j * 16 + l16) * 32 + quad * 8];
        #pragma unroll
        for (int i = 0; i < 4; i++)
            #pragma unroll
            for (int j = 0; j < 4; j++)
                acc[i][j] = __builtin_amdgcn_mfma_f32_16x16x32_bf16(a[i], b[j], acc[i][j], 0, 0, 0);
    }

    #pragma unroll
    for (int i = 0; i < 4; i++)
        #pragma unroll
        for (int j = 0; j < 4; j++)
            #pragma unroll
            for (int r = 0; r < 4; r++) {
                int row = m_blk + mh + i * 16 + quad * 4 + r;
                int col = ncol0 + nh + j * 16 + l16;
                outb[(long)row * 1024 + col] = f2bf(acc[i][j][r]);
            }
}

// ---------------------------------------------------------------------------
// Repack K and V into MFMA-B-fragment-ready tiles (per bh, per 64-key tile):
//   Kt2 chunks u: element = K[(u>>2)*32+((u>>1)&1)*16+l16][(u&1)*32+quad*8+j]
//   Vt2 chunks (c,j): element = V[key(s)][j*16+l16], s=c*32+quad*8+jj,
//     key(s) = (s>>2)+((s&3)<<4)   (matches flash's b64 P-pack order)
// ---------------------------------------------------------------------------
__global__ __launch_bounds__(256) void repack_kv(const short* __restrict__ Kb,
                                                 const short* __restrict__ Vb,
                                                 short* __restrict__ Kt2,
                                                 short* __restrict__ Vt2) {
    __shared__ short Kl[64][72];
    __shared__ short Vl[64][72];
    int t = blockIdx.x, bh = blockIdx.y;
    int b = bh >> 4, h = bh & 15;
    int tid = threadIdx.x;

    int r  = tid >> 2;
    int cc = (tid & 3) * 16;
    const short* ks = Kb + ((long)b * SEQ + t * 64 + r) * 1024 + h * 64 + cc;
    const short* vs = Vb + ((long)b * SEQ + t * 64 + r) * 1024 + h * 64 + cc;
    *(bf16x8*)&Kl[r][cc]     = *(const bf16x8*)(ks);
    *(bf16x8*)&Kl[r][cc + 8] = *(const bf16x8*)(ks + 8);
    *(bf16x8*)&Vl[r][cc]     = *(const bf16x8*)(vs);
    *(bf16x8*)&Vl[r][cc + 8] = *(const bf16x8*)(vs + 8);
    __syncthreads();

    long obase = (long)bh * (SEQ * 64) + t * 4096;

    #pragma unroll
    for (int ch = 0; ch < 2; ch++) {
        int o = tid * 16 + ch * 8;
        int u = o >> 9, qd = (o >> 7) & 3, l = (o >> 3) & 15;
        int row = (u >> 2) * 32 + ((u >> 1) & 1) * 16 + l;
        int col = (u & 1) * 32 + qd * 8;
        *(bf16x8*)(Kt2 + obase + o) = *(const bf16x8*)&Kl[row][col];
    }
    #pragma unroll
    for (int ch = 0; ch < 2; ch++) {
        int o = tid * 16 + ch * 8;
        int c = o >> 11, j = (o >> 9) & 3, qd = (o >> 7) & 3, l = (o >> 3) & 15;
        int hd = j * 16 + l;
        bf16x8 ov;
        #pragma unroll
        for (int jj = 0; jj < 8; jj++) {
            int s = c * 32 + qd * 8 + jj;
            int key = (s >> 2) + ((s & 3) << 4);
            ov[jj] = Vl[key][hd];
        }
        *(bf16x8*)(Vt2 + obase + o) = ov;
    }
}

// ---------------------------------------------------------------------------
// Flash attention, round-4 structure: SHARED keys, split q.
//   Block = 4 waves x 32 q-rows = 128 q-rows; ALL waves sweep ALL 32
//   key-tiles together. Per iteration the 4 waves load IDENTICAL kf/vf
//   fragments -> first wave misses to L2, other 3 hit L1 (MSHR-merged).
//   R2/R3's 4-way ksplit gave each wave disjoint K/V (zero intra-block
//   reuse, HBM-class latency, FETCH=4.4x working set). This also deletes
//   the 3-round ksplit merge (each wave owns its rows end-to-end).
//   Grid 512 blocks, bijective XCD-chunk swizzle (T1): 64 blocks = 4 bh
//   per XCD = 2 MB K/V -> L2-resident.
//   Register body identical to R2 (64 arch + 64 acc, no spill): kf loaded
//   at loop top (cheap now), vf after S-MFMAs. NO cross-iter prefetch
//   (R3 proved +16 live regs = spill at the 128/thread cap).
//   setprio(1) around MFMA clusters: barrier-free desynced waves (m191).
// ---------------------------------------------------------------------------
__global__ __launch_bounds__(256, 4) void flash_attn(const short* __restrict__ Qb,
                                                     const short* __restrict__ Kt2,
                                                     const short* __restrict__ Vt2,
                                                     short* __restrict__ y) {
    int tid  = threadIdx.x;
    int lane = tid & 63;
    int w    = tid >> 6;
    int quad = lane >> 4;
    int l16  = lane & 15;

    // T1: bijective XCD-chunked swizzle (512 % 8 == 0)
    int bid0 = blockIdx.x;
    int nid  = (bid0 & 7) * 64 + (bid0 >> 3);
    int bh   = nid >> 4;        // 4 consecutive bh per XCD
    int b    = bh >> 4;
    int h    = bh & 15;
    int qw   = (nid & 15) * 128 + w * 32;   // wave-private 32 q-rows

    __shared__ short Ps[4][32 * 72];        // wave-private P tiles (18432 B)
    short* PsW = &Ps[w][0];

    const short* Qrow = Qb + ((long)b * SEQ + qw + l16) * 1024 + h * 64;
    bf16x8 aQ[2][2];
    #pragma unroll
    for (int m = 0; m < 2; m++)
        #pragma unroll
        for (int c = 0; c < 2; c++)
            aQ[m][c] = *(const bf16x8*)(Qrow + (long)(m * 16) * 1024 + c * 32 + quad * 8);

    const short* Ktb = Kt2 + (long)bh * (SEQ * 64);
    const short* Vtb = Vt2 + (long)bh * (SEQ * 64);

    f32x4 O[2][4] = {};
    f32x4 Lacc[2] = {};
    bf16x8 ones;
    #pragma unroll
    for (int i = 0; i < 8; i++) ones[i] = (short)0x3F80;   // bf16 1.0

    for (int t = 0; t < 32; t++) {
        const short* Kt = Ktb + t * 4096;
        const short* Vt = Vtb + t * 4096;

        // K fragment loads (1KB dwordx4; shared across waves -> L1-hot)
        bf16x8 kf[8];
        #pragma unroll
        for (int u = 0; u < 8; u++) kf[u] = *(const bf16x8*)(Kt + u * 512 + lane * 8);

        // S = Q K^T: 2 m-frags x 4 key-cols, 2 chained d-chunks each
        __builtin_amdgcn_s_setprio(1);
        f32x4 z[2][4];
        #pragma unroll
        for (int m = 0; m < 2; m++)
            #pragma unroll
            for (int kc = 0; kc < 4; kc++) {
                f32x4 zz = {};
                zz = __builtin_amdgcn_mfma_f32_16x16x32_bf16(aQ[m][0], kf[2 * kc],     zz, 0, 0, 0);
                z[m][kc] = __builtin_amdgcn_mfma_f32_16x16x32_bf16(aQ[m][1], kf[2 * kc + 1], zz, 0, 0, 0);
            }
        __builtin_amdgcn_s_setprio(0);

        // V fragment loads — issued now, consumed after exp/pack (latency hidden)
        bf16x8 vf[8];
        #pragma unroll
        for (int u = 0; u < 8; u++) vf[u] = *(const bf16x8*)(Vt + u * 512 + lane * 8);

        // p = exp2(z) (raw v_exp_f32); packed bf16 cvt; one b64 write per (m,r)
        #pragma unroll
        for (int m = 0; m < 2; m++)
            #pragma unroll
            for (int r = 0; r < 4; r++) {
                unsigned d0 = pk_bf16(EXP2F(z[m][0][r]), EXP2F(z[m][1][r]));
                unsigned d1 = pk_bf16(EXP2F(z[m][2][r]), EXP2F(z[m][3][r]));
                unsigned long long dd = ((unsigned long long)d1 << 32) | d0;
                *(unsigned long long*)((unsigned*)PsW + (m * 16 + quad * 4 + r) * 36 + 2 * l16) = dd;
            }

        // PV + row-sum (ones-column MFMA); bV shared across both m-frags
        __builtin_amdgcn_s_setprio(1);
        #pragma unroll
        for (int c = 0; c < 2; c++) {
            bf16x8 aP0 = *(const bf16x8*)(PsW + (l16) * 72      + c * 32 + quad * 8);
            bf16x8 aP1 = *(const bf16x8*)(PsW + (16 + l16) * 72 + c * 32 + quad * 8);
            Lacc[0] = __builtin_amdgcn_mfma_f32_16x16x32_bf16(aP0, ones, Lacc[0], 0, 0, 0);
            Lacc[1] = __builtin_amdgcn_mfma_f32_16x16x32_bf16(aP1, ones, Lacc[1], 0, 0, 0);
            #pragma unroll
            for (int j = 0; j < 4; j++) {
                O[0][j] = __builtin_amdgcn_mfma_f32_16x16x32_bf16(aP0, vf[c * 4 + j], O[0][j], 0, 0, 0);
                O[1][j] = __builtin_amdgcn_mfma_f32_16x16x32_bf16(aP1, vf[c * 4 + j], O[1][j], 0, 0, 0);
            }
        }
        __builtin_amdgcn_s_setprio(0);
    }

    // direct epilogue: each wave owns its 32 rows — no merge, no barrier
    #pragma unroll
    for (int m = 0; m < 2; m++) {
        f32x4 rl;
        #pragma unroll
        for (int r = 0; r < 4; r++) rl[r] = 1.0f / Lacc[m][r];
        #pragma unroll
        for (int j = 0; j < 4; j++)
            #pragma unroll
            for (int r = 0; r < 4; r++) {
                int row = qw + m * 16 + quad * 4 + r;
                y[((long)b * SEQ + row) * D_MODEL + h * HD + j * 16 + l16] =
                    f2bf(O[m][j][r] * rl[r]);
            }
    }
}

// ---------------------------------------------------------------------------
// Workspace (48 MB): Qb@0, Kb@8M (yb aliases after repack), Vb@16M,
// Kt2@24M, Vt2@32M, WqkvT@40M, WoT@46M. x_bf scratched in d_out.
// ---------------------------------------------------------------------------
extern "C" void kernel_launch(void* const* d_in, const int* in_sizes, int n_in,
                              void* d_out, int out_size, void* d_ws, size_t ws_size,
                              hipStream_t stream) {
    const float* x    = (const float*)d_in[0];
    const float* Wqkv = (const float*)d_in[1];
    const float* Wo   = (const float*)d_in[2];

    char* ws = (char*)d_ws;
    short* Qb    = (short*)(ws);
    short* Kb    = (short*)(ws + 8388608);
    short* Vb    = (short*)(ws + 16777216);
    short* Kt2   = (short*)(ws + 25165824);
    short* Vt2   = (short*)(ws + 33554432);
    short* WqkvT = (short*)(ws + 41943040);
    short* WoT   = (short*)(ws + 48234496);
    short* x_bf  = (short*)d_out;            // scratch in d_out (16 MB fp32)
    short* yb    = Kb;                       // Kb dead after repack_kv

    const float cexp = 0.125f * 1.4426950408889634f;  // 1/sqrt(64) * log2(e)

    prep_kernel<<<8192, 256, 0, stream>>>(x, x_bf, Wqkv, WqkvT, Wo, WoT, cexp);

    gemm_qkv<<<dim3(3 * D_MODEL / 128, NTOK / 128), 256, 0, stream>>>(
        x_bf, WqkvT, Qb, Kb, Vb);

    repack_kv<<<dim3(SEQ / 64, BATCH * NHEADS), 256, 0, stream>>>(Kb, Vb, Kt2, Vt2);

    flash_attn<<<512, 256, 0, stream>>>(Qb, Kt2, Vt2, yb);

    gemm_out<<<dim3(D_MODEL / 64, NTOK / 128), 256, 0, stream>>>(
        yb, WoT, (float*)d_out, NTOK, D_MODEL, D_MODEL);
}